// Round 6
// baseline (743.493 us; speedup 1.0000x reference)
//
#include <hip/hip_runtime.h>
#include <cstdint>

#define D 128
#define BKT_SHIFT 8
#define BKT_CAP 5120
#define EDGES_PER_BLOCK 4096
#define NREP 8
#define LCAP 1536   // LDS edge-index buffer per 64-row tile (avg 1024, ~16 sigma headroom)

typedef __attribute__((ext_vector_type(4))) float floatx4;
typedef __attribute__((ext_vector_type(4))) _Float16 half4;
typedef __attribute__((ext_vector_type(8))) _Float16 half8;

__device__ __forceinline__ float elu_f(float x) {
    return x > 0.0f ? x : __expf(x) - 1.0f;
}

// ================= bucketed CSR build (bump-allocated, no prepass) =================
__global__ __launch_bounds__(256) void bucket_scatter_kernel(
    const int* __restrict__ src, const int* __restrict__ dst,
    int* __restrict__ gcursor, int2* __restrict__ staging, int E, int NB) {
    __shared__ int lcnt[512];
    __shared__ int lbase[512];
    int t = threadIdx.x;
    lcnt[t] = 0; lcnt[t + 256] = 0;
    __syncthreads();
    int base = blockIdx.x * EDGES_PER_BLOCK;
    int s_[16], d_[16], r_[16];
#pragma unroll
    for (int i = 0; i < 16; ++i) {
        int idx = base + i * 256 + t;
        if (idx < E) {
            s_[i] = src[idx];
            d_[i] = dst[idx];
            r_[i] = atomicAdd(&lcnt[d_[i] >> BKT_SHIFT], 1);
        }
    }
    __syncthreads();
    for (int b = t; b < NB; b += 256) {
        int c = lcnt[b];
        if (c) lbase[b] = atomicAdd(&gcursor[b], c);
    }
    __syncthreads();
#pragma unroll
    for (int i = 0; i < 16; ++i) {
        int idx = base + i * 256 + t;
        if (idx < E) {
            int bkt = d_[i] >> BKT_SHIFT;
            staging[lbase[bkt] + r_[i]] = make_int2(s_[i], d_[i]);
        }
    }
}

__global__ __launch_bounds__(256) void bucket_build_kernel(
    const int2* __restrict__ staging, const int* __restrict__ gcursor,
    int* __restrict__ rowstart, int* __restrict__ rowend,
    int* __restrict__ col, int N) {
    __shared__ int hcnt[256];
    __shared__ int hoff[256];
    int t = threadIdx.x;
    int node0 = blockIdx.x << BKT_SHIFT;
    int off0 = blockIdx.x * BKT_CAP;
    int off1 = gcursor[blockIdx.x];
    hcnt[t] = 0;
    __syncthreads();
    for (int i = off0 + t; i < off1; i += 256)
        atomicAdd(&hcnt[staging[i].y - node0], 1);
    __syncthreads();
    int deg = hcnt[t];
    hoff[t] = deg;
    __syncthreads();
    for (int off = 1; off < 256; off <<= 1) {
        int u = (t >= off) ? hoff[t - off] : 0;
        __syncthreads();
        hoff[t] += u;
        __syncthreads();
    }
    int myoff = (t == 0) ? 0 : hoff[t - 1];
    __syncthreads();
    hoff[t] = myoff;
    hcnt[t] = 0;
    if (node0 + t < N) {
        rowstart[node0 + t] = off0 + myoff;
        rowend[node0 + t] = off0 + myoff + deg;
    }
    __syncthreads();
    for (int i = off0 + t; i < off1; i += 256) {
        int2 p = staging[i];
        int dl = p.y - node0;
        int pos = off0 + hoff[dl] + atomicAdd(&hcnt[dl], 1);
        col[pos] = p.x;
    }
}

// ---------------- merged prep: to_half (sliced layout) + wprep + init_cursor ----------------
// h_sl layout: [8 slices][N][16 halves]  (slice = channel/16) -> one slice = 3.2MB, fits one XCD L2.
__global__ __launch_bounds__(256) void prep_kernel(
    const float* __restrict__ x, _Float16* __restrict__ hsl, int n4, int N,
    const float* __restrict__ W1, const float* __restrict__ W2,
    _Float16* __restrict__ Wph, _Float16* __restrict__ Wpl, int wtot,
    int* __restrict__ gcursor, int NB, int nbh, int nbw) {
    int bid = blockIdx.x;
    int t = threadIdx.x;
    if (bid < nbh) {
        int i = bid * 256 + t;
        if (i >= n4) return;
        float4 v = ((const float4*)x)[i];
        half4 h = {(_Float16)v.x, (_Float16)v.y, (_Float16)v.z, (_Float16)v.w};
        int nrow = i >> 5;          // 32 float4 per row
        int c4 = (i & 31) * 4;      // channel offset
        int sl = c4 >> 4, cin = c4 & 15;
        *(half4*)(hsl + ((size_t)sl * N + nrow) * 16 + cin) = h;
    } else if (bid < nbh + nbw) {
        int idx = (bid - nbh) * 256 + t;
        if (idx >= wtot) return;
        int mat = idx >> 14;
        int rem = idx & 16383;
        int tile = rem >> 9;
        int lane = (rem >> 3) & 63;
        int j = rem & 7;
        int ks = tile >> 3, nt = tile & 7;
        int n = nt * 16 + (lane & 15);
        int k = ks * 32 + (lane >> 4) * 8 + j;
        int l = mat >> 1;
        const float* W = (mat & 1) ? W2 : W1;
        float v = W[(size_t)l * D * D + k * D + n];
        _Float16 h = (_Float16)v;
        _Float16 lo = (_Float16)(v - (float)h);
        Wph[idx] = h;
        Wpl[idx] = lo;
    } else {
        int i = (bid - nbh - nbw) * 256 + t;
        if (i < NB) gcursor[i] = i * BKT_CAP;
    }
}

// ---------------- channel-sliced gather: agg_sl[s][node] = h_sl[s][node] + sum_j h_sl[s][j] ----------------
// grid = rowtiles*8, slice = bid&7. With round-robin block->XCD dispatch, XCD k only touches
// slice k (3.2MB, L2-resident). col staged via non-temporal loads; agg written non-temporal
// so streams don't evict the resident h slice.
__global__ __launch_bounds__(256) void agg_slice_kernel(
    const _Float16* __restrict__ hsl,
    const int* __restrict__ rowstart, const int* __restrict__ rowend,
    const int* __restrict__ col,
    _Float16* __restrict__ aggsl, int N) {
    __shared__ int lcol[LCAP];
    __shared__ int srow[65];
    __shared__ float pf[64][2][8];
    const int tid = threadIdx.x;
    const int s = blockIdx.x & 7;
    const int row0 = (blockIdx.x >> 3) * 64;
    const int lastrow = (row0 + 63 < N) ? row0 + 63 : N - 1;
    const int eb0 = rowstart[row0];
    const int eb1 = rowend[lastrow];
    if (tid < 64) {
        int rr = row0 + tid;
        srow[tid] = (rr < N) ? rowstart[rr] : eb1;
    }
    if (tid == 64) srow[64] = eb1;
    for (int k = eb0 + tid; k < eb1 && (k - eb0) < LCAP; k += 256)
        lcol[k - eb0] = __builtin_nontemporal_load(&col[k]);
    __syncthreads();

    const int q2 = tid & 1;        // which half8 of the 32B slice row
    const int g  = (tid >> 1) & 1; // edge parity
    const int r  = tid >> 2;       // 0..63
    const int node = row0 + r;
    const _Float16* hb = hsl + (size_t)s * N * 16;
    float a0 = 0.f, a1 = 0.f, a2 = 0.f, a3 = 0.f;
    float a4 = 0.f, a5 = 0.f, a6 = 0.f, a7 = 0.f;
#define LIDX(ee) ((((ee) - eb0) < LCAP) ? lcol[(ee) - eb0] : col[(ee)])
    if (node < N) {
        int e1 = srow[r + 1];
        int e = srow[r] + g;
        // 8-deep batches, stride 2 (parity-split between g=0/1 threads)
        for (; e + 14 < e1; e += 16) {
            int j0 = LIDX(e),      j1 = LIDX(e + 2),  j2 = LIDX(e + 4),  j3 = LIDX(e + 6);
            int j4 = LIDX(e + 8),  j5 = LIDX(e + 10), j6 = LIDX(e + 12), j7 = LIDX(e + 14);
            half8 v0 = *(const half8*)(hb + (uint32_t)j0 * 16 + q2 * 8);
            half8 v1 = *(const half8*)(hb + (uint32_t)j1 * 16 + q2 * 8);
            half8 v2 = *(const half8*)(hb + (uint32_t)j2 * 16 + q2 * 8);
            half8 v3 = *(const half8*)(hb + (uint32_t)j3 * 16 + q2 * 8);
            half8 v4 = *(const half8*)(hb + (uint32_t)j4 * 16 + q2 * 8);
            half8 v5 = *(const half8*)(hb + (uint32_t)j5 * 16 + q2 * 8);
            half8 v6 = *(const half8*)(hb + (uint32_t)j6 * 16 + q2 * 8);
            half8 v7 = *(const half8*)(hb + (uint32_t)j7 * 16 + q2 * 8);
            a0 += (((float)v0[0] + (float)v1[0]) + ((float)v2[0] + (float)v3[0]))
                + (((float)v4[0] + (float)v5[0]) + ((float)v6[0] + (float)v7[0]));
            a1 += (((float)v0[1] + (float)v1[1]) + ((float)v2[1] + (float)v3[1]))
                + (((float)v4[1] + (float)v5[1]) + ((float)v6[1] + (float)v7[1]));
            a2 += (((float)v0[2] + (float)v1[2]) + ((float)v2[2] + (float)v3[2]))
                + (((float)v4[2] + (float)v5[2]) + ((float)v6[2] + (float)v7[2]));
            a3 += (((float)v0[3] + (float)v1[3]) + ((float)v2[3] + (float)v3[3]))
                + (((float)v4[3] + (float)v5[3]) + ((float)v6[3] + (float)v7[3]));
            a4 += (((float)v0[4] + (float)v1[4]) + ((float)v2[4] + (float)v3[4]))
                + (((float)v4[4] + (float)v5[4]) + ((float)v6[4] + (float)v7[4]));
            a5 += (((float)v0[5] + (float)v1[5]) + ((float)v2[5] + (float)v3[5]))
                + (((float)v4[5] + (float)v5[5]) + ((float)v6[5] + (float)v7[5]));
            a6 += (((float)v0[6] + (float)v1[6]) + ((float)v2[6] + (float)v3[6]))
                + (((float)v4[6] + (float)v5[6]) + ((float)v6[6] + (float)v7[6]));
            a7 += (((float)v0[7] + (float)v1[7]) + ((float)v2[7] + (float)v3[7]))
                + (((float)v4[7] + (float)v5[7]) + ((float)v6[7] + (float)v7[7]));
        }
        // predicated tail batch (clamped indices, float masks)
        if (e < e1) {
            int last = e1 - 1;
            int e0c = e;
            int e1c = e + 2  > last ? last : e + 2,  e2c = e + 4  > last ? last : e + 4;
            int e3c = e + 6  > last ? last : e + 6,  e4c = e + 8  > last ? last : e + 8;
            int e5c = e + 10 > last ? last : e + 10, e6c = e + 12 > last ? last : e + 12;
            int e7c = e + 14 > last ? last : e + 14;
            float m1 = (e + 2  <= last) ? 1.f : 0.f, m2 = (e + 4  <= last) ? 1.f : 0.f;
            float m3 = (e + 6  <= last) ? 1.f : 0.f, m4 = (e + 8  <= last) ? 1.f : 0.f;
            float m5 = (e + 10 <= last) ? 1.f : 0.f, m6 = (e + 12 <= last) ? 1.f : 0.f;
            float m7 = (e + 14 <= last) ? 1.f : 0.f;
            int j0 = LIDX(e0c), j1 = LIDX(e1c), j2 = LIDX(e2c), j3 = LIDX(e3c);
            int j4 = LIDX(e4c), j5 = LIDX(e5c), j6 = LIDX(e6c), j7 = LIDX(e7c);
            half8 v0 = *(const half8*)(hb + (uint32_t)j0 * 16 + q2 * 8);
            half8 v1 = *(const half8*)(hb + (uint32_t)j1 * 16 + q2 * 8);
            half8 v2 = *(const half8*)(hb + (uint32_t)j2 * 16 + q2 * 8);
            half8 v3 = *(const half8*)(hb + (uint32_t)j3 * 16 + q2 * 8);
            half8 v4 = *(const half8*)(hb + (uint32_t)j4 * 16 + q2 * 8);
            half8 v5 = *(const half8*)(hb + (uint32_t)j5 * 16 + q2 * 8);
            half8 v6 = *(const half8*)(hb + (uint32_t)j6 * 16 + q2 * 8);
            half8 v7 = *(const half8*)(hb + (uint32_t)j7 * 16 + q2 * 8);
            a0 += (float)v0[0] + m1 * (float)v1[0] + m2 * (float)v2[0] + m3 * (float)v3[0]
                + m4 * (float)v4[0] + m5 * (float)v5[0] + m6 * (float)v6[0] + m7 * (float)v7[0];
            a1 += (float)v0[1] + m1 * (float)v1[1] + m2 * (float)v2[1] + m3 * (float)v3[1]
                + m4 * (float)v4[1] + m5 * (float)v5[1] + m6 * (float)v6[1] + m7 * (float)v7[1];
            a2 += (float)v0[2] + m1 * (float)v1[2] + m2 * (float)v2[2] + m3 * (float)v3[2]
                + m4 * (float)v4[2] + m5 * (float)v5[2] + m6 * (float)v6[2] + m7 * (float)v7[2];
            a3 += (float)v0[3] + m1 * (float)v1[3] + m2 * (float)v2[3] + m3 * (float)v3[3]
                + m4 * (float)v4[3] + m5 * (float)v5[3] + m6 * (float)v6[3] + m7 * (float)v7[3];
            a4 += (float)v0[4] + m1 * (float)v1[4] + m2 * (float)v2[4] + m3 * (float)v3[4]
                + m4 * (float)v4[4] + m5 * (float)v5[4] + m6 * (float)v6[4] + m7 * (float)v7[4];
            a5 += (float)v0[5] + m1 * (float)v1[5] + m2 * (float)v2[5] + m3 * (float)v3[5]
                + m4 * (float)v4[5] + m5 * (float)v5[5] + m6 * (float)v6[5] + m7 * (float)v7[5];
            a6 += (float)v0[6] + m1 * (float)v1[6] + m2 * (float)v2[6] + m3 * (float)v3[6]
                + m4 * (float)v4[6] + m5 * (float)v5[6] + m6 * (float)v6[6] + m7 * (float)v7[6];
            a7 += (float)v0[7] + m1 * (float)v1[7] + m2 * (float)v2[7] + m3 * (float)v3[7]
                + m4 * (float)v4[7] + m5 * (float)v5[7] + m6 * (float)v6[7] + m7 * (float)v7[7];
        }
    }
#undef LIDX
    if (g == 1) {
        pf[r][q2][0] = a0; pf[r][q2][1] = a1; pf[r][q2][2] = a2; pf[r][q2][3] = a3;
        pf[r][q2][4] = a4; pf[r][q2][5] = a5; pf[r][q2][6] = a6; pf[r][q2][7] = a7;
    }
    __syncthreads();
    if (g == 0 && node < N) {
        half8 sf = *(const half8*)(hb + (uint32_t)node * 16 + q2 * 8);
        a0 += (float)sf[0] + pf[r][q2][0];
        a1 += (float)sf[1] + pf[r][q2][1];
        a2 += (float)sf[2] + pf[r][q2][2];
        a3 += (float)sf[3] + pf[r][q2][3];
        a4 += (float)sf[4] + pf[r][q2][4];
        a5 += (float)sf[5] + pf[r][q2][5];
        a6 += (float)sf[6] + pf[r][q2][6];
        a7 += (float)sf[7] + pf[r][q2][7];
        half8 hv = {(_Float16)a0, (_Float16)a1, (_Float16)a2, (_Float16)a3,
                    (_Float16)a4, (_Float16)a5, (_Float16)a6, (_Float16)a7};
        __builtin_nontemporal_store(hv, (half8*)(aggsl + ((size_t)s * N + node) * 16 + q2 * 8));
    }
}

// ---------------- MFMA GEMM (fp16 A, fp16 hi/lo W, 2 terms), 64x128 tile ----------------
// SLICED_IN: A staged from agg_sl [8][N][16] (dense read). else: A = elu(Z*scale+shift), BN fused.
// SLICED_OUT: write h_sl [8][N][16]. POOL (layer 3): segment-reduce tile into pooled/cnt.
template <bool SLICED_IN, bool ELU_OUT, bool STATS, bool POOL, bool SLICED_OUT>
__global__ __launch_bounds__(256, 8) void gemm_mfma(
    const _Float16* __restrict__ Ain,
    const _Float16* __restrict__ Wph, const _Float16* __restrict__ Wpl,
    const float* __restrict__ bias,
    const float* __restrict__ colsum_in, const float* __restrict__ gamma,
    const float* __restrict__ beta,
    _Float16* __restrict__ outp16, float* __restrict__ colsum_out,
    const int* __restrict__ batchg, float* __restrict__ pooled, float* __restrict__ cnt,
    int N) {
    __shared__ _Float16 sA[64 * 136];
    __shared__ float bnsum[2 * D];
    __shared__ float s_sc[D];
    __shared__ float s_sh[D];
    const int tid = threadIdx.x;
    const int row0 = blockIdx.x * 64;

    if (STATS && tid < 2 * D) bnsum[tid] = 0.f;

    if (SLICED_IN) {
#pragma unroll
        for (int it = 0; it < 4; ++it) {
            int idx = tid + it * 256;
            int r = idx >> 4;
            int q = idx & 15;
            int gr = row0 + r;
            half8 z = {};
            if (gr < N)
                z = *(const half8*)(Ain + ((size_t)(q >> 1) * N + gr) * 16 + (q & 1) * 8);
            *(half8*)&sA[r * 136 + q * 8] = z;
        }
    } else {
        if (tid < D) {
            float s = 0.f, s2 = 0.f;
#pragma unroll
            for (int rp = 0; rp < NREP; ++rp) {
                s  += colsum_in[rp * 2 * D + tid];
                s2 += colsum_in[rp * 2 * D + D + tid];
            }
            float invN = 1.0f / (float)N;
            float mu = s * invN;
            float var = s2 * invN - mu * mu;
            float rs = rsqrtf(var + 1e-5f);
            float sc = gamma[tid] * rs;
            s_sc[tid] = sc;
            s_sh[tid] = beta[tid] - mu * sc;
        }
        __syncthreads();
#pragma unroll
        for (int it = 0; it < 4; ++it) {
            int idx = tid + it * 256;
            int r = idx >> 4;           // 0..63
            int q8 = (idx & 15) * 8;    // channel offset
            int gr = row0 + r;
            half8 z = {};
            if (gr < N) z = *(const half8*)&Ain[(size_t)gr * D + q8];
            float v0 = elu_f((float)z[0] * s_sc[q8 + 0] + s_sh[q8 + 0]);
            float v1 = elu_f((float)z[1] * s_sc[q8 + 1] + s_sh[q8 + 1]);
            float v2 = elu_f((float)z[2] * s_sc[q8 + 2] + s_sh[q8 + 2]);
            float v3 = elu_f((float)z[3] * s_sc[q8 + 3] + s_sh[q8 + 3]);
            float v4 = elu_f((float)z[4] * s_sc[q8 + 4] + s_sh[q8 + 4]);
            float v5 = elu_f((float)z[5] * s_sc[q8 + 5] + s_sh[q8 + 5]);
            float v6 = elu_f((float)z[6] * s_sc[q8 + 6] + s_sh[q8 + 6]);
            float v7 = elu_f((float)z[7] * s_sc[q8 + 7] + s_sh[q8 + 7]);
            half8 hv = {(_Float16)v0, (_Float16)v1, (_Float16)v2, (_Float16)v3,
                        (_Float16)v4, (_Float16)v5, (_Float16)v6, (_Float16)v7};
            *(half8*)&sA[r * 136 + q8] = hv;
        }
    }
    __syncthreads();

    const int wave = tid >> 6, lane = tid & 63;
    const int wm = wave >> 1, wn = wave & 1;
    const int l15 = lane & 15, quad = lane >> 4;
    const half8* bph = (const half8*)Wph;
    const half8* bpl = (const half8*)Wpl;

    floatx4 acc[2][4];
#pragma unroll
    for (int mt = 0; mt < 2; ++mt)
#pragma unroll
        for (int nt = 0; nt < 4; ++nt)
            acc[mt][nt] = (floatx4){0.f, 0.f, 0.f, 0.f};

#pragma unroll
    for (int ks = 0; ks < 4; ++ks) {
        const int kf = ks * 32 + quad * 8;
        half8 ah[2];
#pragma unroll
        for (int mt = 0; mt < 2; ++mt)
            ah[mt] = *(const half8*)&sA[(wm * 32 + mt * 16 + l15) * 136 + kf];
#pragma unroll
        for (int nt = 0; nt < 4; ++nt) {
            int tIdx = (ks * 8 + wn * 4 + nt) * 64 + lane;
            half8 bh = bph[tIdx];
            half8 bl = bpl[tIdx];
            acc[0][nt] = __builtin_amdgcn_mfma_f32_16x16x32_f16(ah[0], bh, acc[0][nt], 0, 0, 0);
            acc[1][nt] = __builtin_amdgcn_mfma_f32_16x16x32_f16(ah[1], bh, acc[1][nt], 0, 0, 0);
            acc[0][nt] = __builtin_amdgcn_mfma_f32_16x16x32_f16(ah[0], bl, acc[0][nt], 0, 0, 0);
            acc[1][nt] = __builtin_amdgcn_mfma_f32_16x16x32_f16(ah[1], bl, acc[1][nt], 0, 0, 0);
        }
    }

    int* sbatch = (int*)s_sc;  // reuse (stage phase done)
    if (POOL) {
        if (tid < 64) {
            int rr = row0 + tid;
            sbatch[tid] = (rr < N) ? batchg[rr] : -1;
        }
        __syncthreads();   // all waves done reading sA before overwrite
    }

#pragma unroll
    for (int nt = 0; nt < 4; ++nt) {
        int c = wn * 64 + nt * 16 + l15;
        float b = bias[c];
        float s = 0.f, s2 = 0.f;
#pragma unroll
        for (int mt = 0; mt < 2; ++mt) {
#pragma unroll
            for (int r = 0; r < 4; ++r) {
                int rl = wm * 32 + mt * 16 + quad * 4 + r;
                int gm = row0 + rl;
                float v = acc[mt][nt][r] + b;
                if (ELU_OUT) v = elu_f(v);
                if (POOL) {
                    if (gm < N) sA[rl * 136 + c] = (_Float16)v;
                } else if (gm < N) {
                    if (SLICED_OUT)
                        outp16[((size_t)(c >> 4) * N + gm) * 16 + (c & 15)] = (_Float16)v;
                    else
                        outp16[(size_t)gm * D + c] = (_Float16)v;
                    if (STATS) { s += v; s2 += v * v; }
                }
            }
        }
        if (STATS) {
            atomicAdd(&bnsum[c], s);
            atomicAdd(&bnsum[D + c], s2);
        }
    }
    if (STATS) {
        __syncthreads();
        float* rep = colsum_out + (size_t)(blockIdx.x & (NREP - 1)) * 2 * D;
        if (tid < D) {
            atomicAdd(&rep[tid], bnsum[tid]);
            atomicAdd(&rep[D + tid], bnsum[D + tid]);
        }
    }
    if (POOL) {
        __syncthreads();   // tile dump complete
        int c = tid & 127, half = tid >> 7;
        int rb = half * 32;
        int cur = -1; float pacc = 0.f; float cc = 0.f;
        for (int i = 0; i < 32; ++i) {
            int r = rb + i;
            int gm = row0 + r;
            if (gm >= N) break;
            int g = sbatch[r];
            if (g != cur) {
                if (cur >= 0) {
                    atomicAdd(&pooled[(size_t)cur * D + c], pacc);
                    if (c == 0) atomicAdd(&cnt[cur], cc);
                }
                cur = g; pacc = 0.f; cc = 0.f;
            }
            pacc += (float)sA[r * 136 + c];
            cc += 1.f;
        }
        if (cur >= 0) {
            atomicAdd(&pooled[(size_t)cur * D + c], pacc);
            if (c == 0) atomicAdd(&cnt[cur], cc);
        }
    }
}

__global__ void final_linear_kernel(const float* __restrict__ pooled,
                                    const float* __restrict__ cnt,
                                    const float* __restrict__ linW,
                                    const float* __restrict__ linb,
                                    float* __restrict__ out, int G) {
    int t = blockIdx.x * blockDim.x + threadIdx.x;
    if (t >= G * 2) return;
    int g = t >> 1, o = t & 1;
    float inv = 1.0f / fmaxf(cnt[g], 1.0f);
    float s = linb[o];
    for (int c = 0; c < D; ++c)
        s += pooled[(size_t)g * D + c] * inv * linW[c * 2 + o];
    out[t] = s;
}

extern "C" void kernel_launch(void* const* d_in, const int* in_sizes, int n_in,
                              void* d_out, int out_size, void* d_ws, size_t ws_size,
                              hipStream_t stream) {
    const float* x      = (const float*)d_in[0];
    const int*  eidx    = (const int*)d_in[1];
    const int*  batch   = (const int*)d_in[2];
    const float* W1     = (const float*)d_in[3];
    const float* b1     = (const float*)d_in[4];
    const float* gamma  = (const float*)d_in[5];
    const float* beta   = (const float*)d_in[6];
    const float* W2     = (const float*)d_in[7];
    const float* b2     = (const float*)d_in[8];
    const float* linW   = (const float*)d_in[9];
    const float* linb   = (const float*)d_in[10];
    float* out = (float*)d_out;

    const int N = in_sizes[0] / D;
    const int E = in_sizes[1] / 2;
    const int L = in_sizes[3] / (D * D);
    const int G = out_size / 2;
    const int* esrc = eidx;
    const int* edst = eidx + E;
    const int NB = (N + 255) >> 8;

    size_t off = 0;
    auto carve = [&](size_t bytes) -> void* {
        void* p = (char*)d_ws + off;
        off += (bytes + 255) & ~(size_t)255;
        return p;
    };
    const size_t ND = (size_t)N * D;
    const int WTOT = 2 * L * D * D;
    _Float16* z16   = (_Float16*)carve(ND * 2);      // row-major; aliased as CSR staging (16MB <= 25.6MB)
    _Float16* hsl   = (_Float16*)carve(ND * 2);      // sliced [8][N][16]
    _Float16* aggsl = (_Float16*)carve(ND * 2);      // sliced [8][N][16]
    _Float16* Wph = (_Float16*)carve((size_t)WTOT * 2);
    _Float16* Wpl = (_Float16*)carve((size_t)WTOT * 2);
    int* rowstart = (int*)carve((size_t)N * 4);
    int* rowend   = (int*)carve((size_t)N * 4);
    int* col      = (int*)carve((size_t)NB * BKT_CAP * 4);
    // colsum4 + pooled + cnt carved contiguously -> single memset
    const size_t cs_bytes = ((size_t)4 * NREP * 2 * D * 4 + 255) & ~(size_t)255;
    const size_t pl_bytes = ((size_t)G * D * 4 + 255) & ~(size_t)255;
    float* colsum4 = (float*)carve((size_t)4 * NREP * 2 * D * 4);
    float* pooled  = (float*)carve((size_t)G * D * 4);
    float* cnt     = (float*)carve((size_t)G * 4);
    int* gcursor   = (int*)carve(512 * 4);
    int2* staging = (int2*)z16;
    (void)ws_size; (void)n_in;

    hipMemsetAsync(colsum4, 0, cs_bytes + pl_bytes + (size_t)G * 4, stream);

    const int EB = (E + EDGES_PER_BLOCK - 1) / EDGES_PER_BLOCK;
    const int n4 = (int)(ND / 4);
    const int nbh = (n4 + 255) / 256;
    const int nbw = (WTOT + 255) / 256;
    const int nbc = (NB + 255) / 256;
    prep_kernel<<<nbh + nbw + nbc, 256, 0, stream>>>(
        x, hsl, n4, N, W1, W2, Wph, Wpl, WTOT, gcursor, NB, nbh, nbw);
    bucket_scatter_kernel<<<EB, 256, 0, stream>>>(esrc, edst, gcursor, staging, E, NB);
    bucket_build_kernel<<<NB, 256, 0, stream>>>(staging, gcursor, rowstart, rowend, col, N);

    const int RT = (N + 63) / 64;
    for (int l = 0; l < L; ++l) {
        float* colsum = colsum4 + (size_t)l * NREP * 2 * D;
        agg_slice_kernel<<<RT * 8, 256, 0, stream>>>(hsl, rowstart, rowend, col, aggsl, N);
        gemm_mfma<true, false, true, false, false><<<RT, 256, 0, stream>>>(
            aggsl,
            Wph + (size_t)(l * 2) * D * D, Wpl + (size_t)(l * 2) * D * D,
            b1 + (size_t)l * D, nullptr, nullptr, nullptr, z16, colsum,
            nullptr, nullptr, nullptr, N);
        if (l < L - 1) {
            gemm_mfma<false, true, false, false, true><<<RT, 256, 0, stream>>>(
                z16,
                Wph + (size_t)(l * 2 + 1) * D * D, Wpl + (size_t)(l * 2 + 1) * D * D,
                b2 + (size_t)l * D, colsum, gamma + (size_t)l * D, beta + (size_t)l * D,
                hsl, nullptr, nullptr, nullptr, nullptr, N);
        } else {
            gemm_mfma<false, true, false, true, false><<<RT, 256, 0, stream>>>(
                z16,
                Wph + (size_t)(l * 2 + 1) * D * D, Wpl + (size_t)(l * 2 + 1) * D * D,
                b2 + (size_t)l * D, colsum, gamma + (size_t)l * D, beta + (size_t)l * D,
                nullptr, nullptr, batch, pooled, cnt, N);
        }
    }

    final_linear_kernel<<<(G * 2 + 255) / 256, 256, 0, stream>>>(pooled, cnt, linW, linb, out, G);
}

// Round 7
// 570.611 us; speedup vs baseline: 1.3030x; 1.3030x over previous
//
#include <hip/hip_runtime.h>
#include <cstdint>

#define D 128
#define BKT_SHIFT 8
#define BKT_CAP 5120
#define EDGES_PER_BLOCK 4096
#define NREP 8

typedef __attribute__((ext_vector_type(4))) float floatx4;
typedef __attribute__((ext_vector_type(4))) _Float16 half4;
typedef __attribute__((ext_vector_type(8))) _Float16 half8;

__device__ __forceinline__ float elu_f(float x) {
    return x > 0.0f ? x : __expf(x) - 1.0f;
}

// ================= bucketed CSR build (bump-allocated, no prepass) =================
__global__ __launch_bounds__(256) void bucket_scatter_kernel(
    const int* __restrict__ src, const int* __restrict__ dst,
    int* __restrict__ gcursor, int2* __restrict__ staging, int E, int NB) {
    __shared__ int lcnt[512];
    __shared__ int lbase[512];
    int t = threadIdx.x;
    lcnt[t] = 0; lcnt[t + 256] = 0;
    __syncthreads();
    int base = blockIdx.x * EDGES_PER_BLOCK;
    int s_[16], d_[16], r_[16];
#pragma unroll
    for (int i = 0; i < 16; ++i) {
        int idx = base + i * 256 + t;
        if (idx < E) {
            s_[i] = src[idx];
            d_[i] = dst[idx];
            r_[i] = atomicAdd(&lcnt[d_[i] >> BKT_SHIFT], 1);
        }
    }
    __syncthreads();
    for (int b = t; b < NB; b += 256) {
        int c = lcnt[b];
        if (c) lbase[b] = atomicAdd(&gcursor[b], c);
    }
    __syncthreads();
#pragma unroll
    for (int i = 0; i < 16; ++i) {
        int idx = base + i * 256 + t;
        if (idx < E) {
            int bkt = d_[i] >> BKT_SHIFT;
            staging[lbase[bkt] + r_[i]] = make_int2(s_[i], d_[i]);
        }
    }
}

__global__ __launch_bounds__(256) void bucket_build_kernel(
    const int2* __restrict__ staging, const int* __restrict__ gcursor,
    int* __restrict__ rowstart, int* __restrict__ rowend,
    int* __restrict__ col, int N) {
    __shared__ int hcnt[256];
    __shared__ int hoff[256];
    int t = threadIdx.x;
    int node0 = blockIdx.x << BKT_SHIFT;
    int off0 = blockIdx.x * BKT_CAP;
    int off1 = gcursor[blockIdx.x];
    hcnt[t] = 0;
    __syncthreads();
    for (int i = off0 + t; i < off1; i += 256)
        atomicAdd(&hcnt[staging[i].y - node0], 1);
    __syncthreads();
    int deg = hcnt[t];
    hoff[t] = deg;
    __syncthreads();
    for (int off = 1; off < 256; off <<= 1) {
        int u = (t >= off) ? hoff[t - off] : 0;
        __syncthreads();
        hoff[t] += u;
        __syncthreads();
    }
    int myoff = (t == 0) ? 0 : hoff[t - 1];
    __syncthreads();
    hoff[t] = myoff;
    hcnt[t] = 0;
    if (node0 + t < N) {
        rowstart[node0 + t] = off0 + myoff;
        rowend[node0 + t] = off0 + myoff + deg;
    }
    __syncthreads();
    for (int i = off0 + t; i < off1; i += 256) {
        int2 p = staging[i];
        int dl = p.y - node0;
        int pos = off0 + hoff[dl] + atomicAdd(&hcnt[dl], 1);
        col[pos] = p.x;
    }
}

// ---------------- merged prep: to_half + wprep + init_cursor ----------------
__global__ __launch_bounds__(256) void prep_kernel(
    const float* __restrict__ x, _Float16* __restrict__ hhalf, int n4,
    const float* __restrict__ W1, const float* __restrict__ W2,
    _Float16* __restrict__ Wph, _Float16* __restrict__ Wpl, int wtot,
    int* __restrict__ gcursor, int NB, int nbh, int nbw) {
    int bid = blockIdx.x;
    int t = threadIdx.x;
    if (bid < nbh) {
        int i = bid * 256 + t;
        if (i >= n4) return;
        float4 v = ((const float4*)x)[i];
        half4 h = {(_Float16)v.x, (_Float16)v.y, (_Float16)v.z, (_Float16)v.w};
        ((half4*)hhalf)[i] = h;
    } else if (bid < nbh + nbw) {
        int idx = (bid - nbh) * 256 + t;
        if (idx >= wtot) return;
        int mat = idx >> 14;
        int rem = idx & 16383;
        int tile = rem >> 9;
        int lane = (rem >> 3) & 63;
        int j = rem & 7;
        int ks = tile >> 3, nt = tile & 7;
        int n = nt * 16 + (lane & 15);
        int k = ks * 32 + (lane >> 4) * 8 + j;
        int l = mat >> 1;
        const float* W = (mat & 1) ? W2 : W1;
        float v = W[(size_t)l * D * D + k * D + n];
        _Float16 h = (_Float16)v;
        _Float16 lo = (_Float16)(v - (float)h);
        Wph[idx] = h;
        Wpl[idx] = lo;
    } else {
        int i = (bid - nbh - nbw) * 256 + t;
        if (i < NB) gcursor[i] = i * BKT_CAP;
    }
}

// ---------------- MFMA GEMM (fp16 A, fp16 hi/lo W, 2 terms), 64x128 tile ----------------
// GATHER: A = h16[node] + sum_neighbors h16[j] (16-deep + 8-deep + predicated-8 batches,
//   direct col[] reads -- LDS staging of CSR metadata was a measured null).
// else: A = elu(Z16*scale+shift), BN fused from 8-replica colsum_in.
// Epilogue: acc -> sA tile (bias/elu applied), then coalesced half8 row stores
//   (16B/lane, replaces 32x 2B scattered stores). POOL: segment-reduce sA into pooled/cnt.
template <bool GATHER, bool ELU_OUT, bool STATS, bool POOL, int MW>
__global__ __launch_bounds__(256, MW) void gemm_mfma(
    const _Float16* __restrict__ Hh,
    const int* __restrict__ rowstart, const int* __restrict__ rowend,
    const int* __restrict__ col,
    const _Float16* __restrict__ Z,
    const _Float16* __restrict__ Wph, const _Float16* __restrict__ Wpl,
    const float* __restrict__ bias,
    const float* __restrict__ colsum_in, const float* __restrict__ gamma,
    const float* __restrict__ beta,
    _Float16* __restrict__ outp16, float* __restrict__ colsum_out,
    const int* __restrict__ batchg, float* __restrict__ pooled, float* __restrict__ cnt,
    int N) {
    __shared__ _Float16 sA[64 * 136];
    __shared__ float bnsum[2 * D];
    __shared__ float s_sc[D];
    __shared__ float s_sh[D];
    const int tid = threadIdx.x;
    const int row0 = blockIdx.x * 64;

    if (STATS && tid < 2 * D) bnsum[tid] = 0.f;

    if (GATHER) {
        const int rg = tid >> 4;     // 0..15 row groups (4 rows each)
        const int q = tid & 15;      // half8 lane (8 channels)
        const half8* hh8 = (const half8*)Hh;
#pragma unroll
        for (int i = 0; i < 4; ++i) {
            int r = rg * 4 + i;
            int node = row0 + r;
            float a0 = 0.f, a1 = 0.f, a2 = 0.f, a3 = 0.f;
            float a4 = 0.f, a5 = 0.f, a6 = 0.f, a7 = 0.f;
            if (node < N) {
                half8 sf = hh8[(uint32_t)(node * 16 + q)];
                a0 = (float)sf[0]; a1 = (float)sf[1]; a2 = (float)sf[2]; a3 = (float)sf[3];
                a4 = (float)sf[4]; a5 = (float)sf[5]; a6 = (float)sf[6]; a7 = (float)sf[7];
                int e0 = rowstart[node], e1 = rowend[node];
                int e = e0;
                // ---- 16-deep full batches ----
                for (; e + 15 < e1; e += 16) {
                    int j0 = col[e],      j1 = col[e + 1],  j2 = col[e + 2],  j3 = col[e + 3];
                    int j4 = col[e + 4],  j5 = col[e + 5],  j6 = col[e + 6],  j7 = col[e + 7];
                    int j8 = col[e + 8],  j9 = col[e + 9],  jA = col[e + 10], jB = col[e + 11];
                    int jC = col[e + 12], jD = col[e + 13], jE = col[e + 14], jF = col[e + 15];
                    half8 v0 = hh8[(uint32_t)(j0 * 16 + q)];
                    half8 v1 = hh8[(uint32_t)(j1 * 16 + q)];
                    half8 v2 = hh8[(uint32_t)(j2 * 16 + q)];
                    half8 v3 = hh8[(uint32_t)(j3 * 16 + q)];
                    half8 v4 = hh8[(uint32_t)(j4 * 16 + q)];
                    half8 v5 = hh8[(uint32_t)(j5 * 16 + q)];
                    half8 v6 = hh8[(uint32_t)(j6 * 16 + q)];
                    half8 v7 = hh8[(uint32_t)(j7 * 16 + q)];
                    half8 v8 = hh8[(uint32_t)(j8 * 16 + q)];
                    half8 v9 = hh8[(uint32_t)(j9 * 16 + q)];
                    half8 vA = hh8[(uint32_t)(jA * 16 + q)];
                    half8 vB = hh8[(uint32_t)(jB * 16 + q)];
                    half8 vC = hh8[(uint32_t)(jC * 16 + q)];
                    half8 vD = hh8[(uint32_t)(jD * 16 + q)];
                    half8 vE = hh8[(uint32_t)(jE * 16 + q)];
                    half8 vF = hh8[(uint32_t)(jF * 16 + q)];
#pragma unroll
                    for (int c = 0; c < 8; ++c) {
                        float s = (((float)v0[c] + (float)v1[c]) + ((float)v2[c] + (float)v3[c]))
                                + (((float)v4[c] + (float)v5[c]) + ((float)v6[c] + (float)v7[c]))
                                + (((float)v8[c] + (float)v9[c]) + ((float)vA[c] + (float)vB[c]))
                                + (((float)vC[c] + (float)vD[c]) + ((float)vE[c] + (float)vF[c]));
                        if (c == 0) a0 += s; else if (c == 1) a1 += s;
                        else if (c == 2) a2 += s; else if (c == 3) a3 += s;
                        else if (c == 4) a4 += s; else if (c == 5) a5 += s;
                        else if (c == 6) a6 += s; else a7 += s;
                    }
                }
                // ---- one plain 8-deep batch ----
                if (e + 7 < e1) {
                    int j0 = col[e],     j1 = col[e + 1], j2 = col[e + 2], j3 = col[e + 3];
                    int j4 = col[e + 4], j5 = col[e + 5], j6 = col[e + 6], j7 = col[e + 7];
                    half8 v0 = hh8[(uint32_t)(j0 * 16 + q)];
                    half8 v1 = hh8[(uint32_t)(j1 * 16 + q)];
                    half8 v2 = hh8[(uint32_t)(j2 * 16 + q)];
                    half8 v3 = hh8[(uint32_t)(j3 * 16 + q)];
                    half8 v4 = hh8[(uint32_t)(j4 * 16 + q)];
                    half8 v5 = hh8[(uint32_t)(j5 * 16 + q)];
                    half8 v6 = hh8[(uint32_t)(j6 * 16 + q)];
                    half8 v7 = hh8[(uint32_t)(j7 * 16 + q)];
                    a0 += (((float)v0[0] + (float)v1[0]) + ((float)v2[0] + (float)v3[0]))
                        + (((float)v4[0] + (float)v5[0]) + ((float)v6[0] + (float)v7[0]));
                    a1 += (((float)v0[1] + (float)v1[1]) + ((float)v2[1] + (float)v3[1]))
                        + (((float)v4[1] + (float)v5[1]) + ((float)v6[1] + (float)v7[1]));
                    a2 += (((float)v0[2] + (float)v1[2]) + ((float)v2[2] + (float)v3[2]))
                        + (((float)v4[2] + (float)v5[2]) + ((float)v6[2] + (float)v7[2]));
                    a3 += (((float)v0[3] + (float)v1[3]) + ((float)v2[3] + (float)v3[3]))
                        + (((float)v4[3] + (float)v5[3]) + ((float)v6[3] + (float)v7[3]));
                    a4 += (((float)v0[4] + (float)v1[4]) + ((float)v2[4] + (float)v3[4]))
                        + (((float)v4[4] + (float)v5[4]) + ((float)v6[4] + (float)v7[4]));
                    a5 += (((float)v0[5] + (float)v1[5]) + ((float)v2[5] + (float)v3[5]))
                        + (((float)v4[5] + (float)v5[5]) + ((float)v6[5] + (float)v7[5]));
                    a6 += (((float)v0[6] + (float)v1[6]) + ((float)v2[6] + (float)v3[6]))
                        + (((float)v4[6] + (float)v5[6]) + ((float)v6[6] + (float)v7[6]));
                    a7 += (((float)v0[7] + (float)v1[7]) + ((float)v2[7] + (float)v3[7]))
                        + (((float)v4[7] + (float)v5[7]) + ((float)v6[7] + (float)v7[7]));
                    e += 8;
                }
                // ---- predicated 8-deep tail (clamped indices, float masks) ----
                if (e < e1) {
                    int last = e1 - 1;
                    int e0c = e,     e1c = e + 1 > last ? last : e + 1;
                    int e2c = e + 2 > last ? last : e + 2, e3c = e + 3 > last ? last : e + 3;
                    int e4c = e + 4 > last ? last : e + 4, e5c = e + 5 > last ? last : e + 5;
                    int e6c = e + 6 > last ? last : e + 6, e7c = e + 7 > last ? last : e + 7;
                    int j0 = col[e0c], j1 = col[e1c], j2 = col[e2c], j3 = col[e3c];
                    int j4 = col[e4c], j5 = col[e5c], j6 = col[e6c], j7 = col[e7c];
                    float m1 = (e + 1 <= last) ? 1.f : 0.f, m2 = (e + 2 <= last) ? 1.f : 0.f;
                    float m3 = (e + 3 <= last) ? 1.f : 0.f, m4 = (e + 4 <= last) ? 1.f : 0.f;
                    float m5 = (e + 5 <= last) ? 1.f : 0.f, m6 = (e + 6 <= last) ? 1.f : 0.f;
                    float m7 = (e + 7 <= last) ? 1.f : 0.f;
                    half8 v0 = hh8[(uint32_t)(j0 * 16 + q)];
                    half8 v1 = hh8[(uint32_t)(j1 * 16 + q)];
                    half8 v2 = hh8[(uint32_t)(j2 * 16 + q)];
                    half8 v3 = hh8[(uint32_t)(j3 * 16 + q)];
                    half8 v4 = hh8[(uint32_t)(j4 * 16 + q)];
                    half8 v5 = hh8[(uint32_t)(j5 * 16 + q)];
                    half8 v6 = hh8[(uint32_t)(j6 * 16 + q)];
                    half8 v7 = hh8[(uint32_t)(j7 * 16 + q)];
                    a0 += (float)v0[0] + m1 * (float)v1[0] + m2 * (float)v2[0] + m3 * (float)v3[0]
                        + m4 * (float)v4[0] + m5 * (float)v5[0] + m6 * (float)v6[0] + m7 * (float)v7[0];
                    a1 += (float)v0[1] + m1 * (float)v1[1] + m2 * (float)v2[1] + m3 * (float)v3[1]
                        + m4 * (float)v4[1] + m5 * (float)v5[1] + m6 * (float)v6[1] + m7 * (float)v7[1];
                    a2 += (float)v0[2] + m1 * (float)v1[2] + m2 * (float)v2[2] + m3 * (float)v3[2]
                        + m4 * (float)v4[2] + m5 * (float)v5[2] + m6 * (float)v6[2] + m7 * (float)v7[2];
                    a3 += (float)v0[3] + m1 * (float)v1[3] + m2 * (float)v2[3] + m3 * (float)v3[3]
                        + m4 * (float)v4[3] + m5 * (float)v5[3] + m6 * (float)v6[3] + m7 * (float)v7[3];
                    a4 += (float)v0[4] + m1 * (float)v1[4] + m2 * (float)v2[4] + m3 * (float)v3[4]
                        + m4 * (float)v4[4] + m5 * (float)v5[4] + m6 * (float)v6[4] + m7 * (float)v7[4];
                    a5 += (float)v0[5] + m1 * (float)v1[5] + m2 * (float)v2[5] + m3 * (float)v3[5]
                        + m4 * (float)v4[5] + m5 * (float)v5[5] + m6 * (float)v6[5] + m7 * (float)v7[5];
                    a6 += (float)v0[6] + m1 * (float)v1[6] + m2 * (float)v2[6] + m3 * (float)v3[6]
                        + m4 * (float)v4[6] + m5 * (float)v5[6] + m6 * (float)v6[6] + m7 * (float)v7[6];
                    a7 += (float)v0[7] + m1 * (float)v1[7] + m2 * (float)v2[7] + m3 * (float)v3[7]
                        + m4 * (float)v4[7] + m5 * (float)v5[7] + m6 * (float)v6[7] + m7 * (float)v7[7];
                }
            }
            half8 hv = {(_Float16)a0, (_Float16)a1, (_Float16)a2, (_Float16)a3,
                        (_Float16)a4, (_Float16)a5, (_Float16)a6, (_Float16)a7};
            *(half8*)&sA[r * 136 + q * 8] = hv;
        }
    } else {
        if (tid < D) {
            float s = 0.f, s2 = 0.f;
#pragma unroll
            for (int rp = 0; rp < NREP; ++rp) {
                s  += colsum_in[rp * 2 * D + tid];
                s2 += colsum_in[rp * 2 * D + D + tid];
            }
            float invN = 1.0f / (float)N;
            float mu = s * invN;
            float var = s2 * invN - mu * mu;
            float rs = rsqrtf(var + 1e-5f);
            float sc = gamma[tid] * rs;
            s_sc[tid] = sc;
            s_sh[tid] = beta[tid] - mu * sc;
        }
        __syncthreads();
#pragma unroll
        for (int it = 0; it < 4; ++it) {
            int idx = tid + it * 256;
            int r = idx >> 4;           // 0..63
            int q8 = (idx & 15) * 8;    // channel offset
            int gr = row0 + r;
            half8 z = {};
            if (gr < N) z = *(const half8*)&Z[(size_t)gr * D + q8];
            float v0 = elu_f((float)z[0] * s_sc[q8 + 0] + s_sh[q8 + 0]);
            float v1 = elu_f((float)z[1] * s_sc[q8 + 1] + s_sh[q8 + 1]);
            float v2 = elu_f((float)z[2] * s_sc[q8 + 2] + s_sh[q8 + 2]);
            float v3 = elu_f((float)z[3] * s_sc[q8 + 3] + s_sh[q8 + 3]);
            float v4 = elu_f((float)z[4] * s_sc[q8 + 4] + s_sh[q8 + 4]);
            float v5 = elu_f((float)z[5] * s_sc[q8 + 5] + s_sh[q8 + 5]);
            float v6 = elu_f((float)z[6] * s_sc[q8 + 6] + s_sh[q8 + 6]);
            float v7 = elu_f((float)z[7] * s_sc[q8 + 7] + s_sh[q8 + 7]);
            half8 hv = {(_Float16)v0, (_Float16)v1, (_Float16)v2, (_Float16)v3,
                        (_Float16)v4, (_Float16)v5, (_Float16)v6, (_Float16)v7};
            *(half8*)&sA[r * 136 + q8] = hv;
        }
    }
    __syncthreads();

    const int wave = tid >> 6, lane = tid & 63;
    const int wm = wave >> 1, wn = wave & 1;
    const int l15 = lane & 15, quad = lane >> 4;
    const half8* bph = (const half8*)Wph;
    const half8* bpl = (const half8*)Wpl;

    floatx4 acc[2][4];
#pragma unroll
    for (int mt = 0; mt < 2; ++mt)
#pragma unroll
        for (int nt = 0; nt < 4; ++nt)
            acc[mt][nt] = (floatx4){0.f, 0.f, 0.f, 0.f};

#pragma unroll
    for (int ks = 0; ks < 4; ++ks) {
        const int kf = ks * 32 + quad * 8;
        half8 ah[2];
#pragma unroll
        for (int mt = 0; mt < 2; ++mt)
            ah[mt] = *(const half8*)&sA[(wm * 32 + mt * 16 + l15) * 136 + kf];
        // stream B per-nt to keep live registers low
#pragma unroll
        for (int nt = 0; nt < 4; ++nt) {
            int tIdx = (ks * 8 + wn * 4 + nt) * 64 + lane;
            half8 bh = bph[tIdx];
            half8 bl = bpl[tIdx];
            acc[0][nt] = __builtin_amdgcn_mfma_f32_16x16x32_f16(ah[0], bh, acc[0][nt], 0, 0, 0);
            acc[1][nt] = __builtin_amdgcn_mfma_f32_16x16x32_f16(ah[1], bh, acc[1][nt], 0, 0, 0);
            acc[0][nt] = __builtin_amdgcn_mfma_f32_16x16x32_f16(ah[0], bl, acc[0][nt], 0, 0, 0);
            acc[1][nt] = __builtin_amdgcn_mfma_f32_16x16x32_f16(ah[1], bl, acc[1][nt], 0, 0, 0);
        }
    }

    // ---- epilogue: acc -> sA tile (bias/elu), stats; then coalesced stores / pool ----
    __syncthreads();   // all waves done reading sA (MFMA phase)
    int* sbatch = (int*)s_sc;  // overlay (s_sc last read pre-MFMA)
    if (POOL && tid < 64) {
        int rr = row0 + tid;
        sbatch[tid] = (rr < N) ? batchg[rr] : -1;
    }
#pragma unroll
    for (int nt = 0; nt < 4; ++nt) {
        int c = wn * 64 + nt * 16 + l15;
        float b = bias[c];
        float s = 0.f, s2 = 0.f;
#pragma unroll
        for (int mt = 0; mt < 2; ++mt) {
#pragma unroll
            for (int r = 0; r < 4; ++r) {
                int rl = wm * 32 + mt * 16 + quad * 4 + r;
                float v = acc[mt][nt][r] + b;
                if (ELU_OUT) v = elu_f(v);
                sA[rl * 136 + c] = (_Float16)v;
                if (STATS && row0 + rl < N) { s += v; s2 += v * v; }
            }
        }
        if (STATS) {
            atomicAdd(&bnsum[c], s);
            atomicAdd(&bnsum[D + c], s2);
        }
    }
    __syncthreads();   // sA + bnsum complete

    if (POOL) {
        int c = tid & 127, hf = tid >> 7;
        int rb = hf * 32;
        int cur = -1; float pacc = 0.f; float cc = 0.f;
        for (int i = 0; i < 32; ++i) {
            int r = rb + i;
            int gm = row0 + r;
            if (gm >= N) break;
            int g = sbatch[r];
            if (g != cur) {
                if (cur >= 0) {
                    atomicAdd(&pooled[(size_t)cur * D + c], pacc);
                    if (c == 0) atomicAdd(&cnt[cur], cc);
                }
                cur = g; pacc = 0.f; cc = 0.f;
            }
            pacc += (float)sA[r * 136 + c];
            cc += 1.f;
        }
        if (cur >= 0) {
            atomicAdd(&pooled[(size_t)cur * D + c], pacc);
            if (c == 0) atomicAdd(&cnt[cur], cc);
        }
    } else {
#pragma unroll
        for (int it = 0; it < 4; ++it) {
            int idx = tid + it * 256;
            int r = idx >> 4;          // 0..63
            int q = idx & 15;          // half8 within row
            int gr = row0 + r;
            if (gr < N)
                *(half8*)&outp16[(size_t)gr * D + q * 8] = *(const half8*)&sA[r * 136 + q * 8];
        }
    }
    if (STATS) {
        float* rep = colsum_out + (size_t)(blockIdx.x & (NREP - 1)) * 2 * D;
        if (tid < D) {
            atomicAdd(&rep[tid], bnsum[tid]);
            atomicAdd(&rep[D + tid], bnsum[D + tid]);
        }
    }
}

__global__ void final_linear_kernel(const float* __restrict__ pooled,
                                    const float* __restrict__ cnt,
                                    const float* __restrict__ linW,
                                    const float* __restrict__ linb,
                                    float* __restrict__ out, int G) {
    int t = blockIdx.x * blockDim.x + threadIdx.x;
    if (t >= G * 2) return;
    int g = t >> 1, o = t & 1;
    float inv = 1.0f / fmaxf(cnt[g], 1.0f);
    float s = linb[o];
    for (int c = 0; c < D; ++c)
        s += pooled[(size_t)g * D + c] * inv * linW[c * 2 + o];
    out[t] = s;
}

extern "C" void kernel_launch(void* const* d_in, const int* in_sizes, int n_in,
                              void* d_out, int out_size, void* d_ws, size_t ws_size,
                              hipStream_t stream) {
    const float* x      = (const float*)d_in[0];
    const int*  eidx    = (const int*)d_in[1];
    const int*  batch   = (const int*)d_in[2];
    const float* W1     = (const float*)d_in[3];
    const float* b1     = (const float*)d_in[4];
    const float* gamma  = (const float*)d_in[5];
    const float* beta   = (const float*)d_in[6];
    const float* W2     = (const float*)d_in[7];
    const float* b2     = (const float*)d_in[8];
    const float* linW   = (const float*)d_in[9];
    const float* linb   = (const float*)d_in[10];
    float* out = (float*)d_out;

    const int N = in_sizes[0] / D;
    const int E = in_sizes[1] / 2;
    const int L = in_sizes[3] / (D * D);
    const int G = out_size / 2;
    const int* esrc = eidx;
    const int* edst = eidx + E;
    const int NB = (N + 255) >> 8;

    size_t off = 0;
    auto carve = [&](size_t bytes) -> void* {
        void* p = (char*)d_ws + off;
        off += (bytes + 255) & ~(size_t)255;
        return p;
    };
    const size_t ND = (size_t)N * D;
    const int WTOT = 2 * L * D * D;
    _Float16* z16   = (_Float16*)carve(ND * 2);      // aliased as CSR staging (12.8MB <= 25.6MB)
    _Float16* hhalf = (_Float16*)carve(ND * 2);
    _Float16* Wph = (_Float16*)carve((size_t)WTOT * 2);
    _Float16* Wpl = (_Float16*)carve((size_t)WTOT * 2);
    int* rowstart = (int*)carve((size_t)N * 4);
    int* rowend   = (int*)carve((size_t)N * 4);
    int* col      = (int*)carve((size_t)NB * BKT_CAP * 4);
    // colsum4 + pooled + cnt carved contiguously -> single memset
    const size_t cs_bytes = ((size_t)4 * NREP * 2 * D * 4 + 255) & ~(size_t)255;
    const size_t pl_bytes = ((size_t)G * D * 4 + 255) & ~(size_t)255;
    float* colsum4 = (float*)carve((size_t)4 * NREP * 2 * D * 4);
    float* pooled  = (float*)carve((size_t)G * D * 4);
    float* cnt     = (float*)carve((size_t)G * 4);
    int* gcursor   = (int*)carve(512 * 4);
    int2* staging = (int2*)z16;
    (void)ws_size; (void)n_in;

    hipMemsetAsync(colsum4, 0, cs_bytes + pl_bytes + (size_t)G * 4, stream);

    const int EB = (E + EDGES_PER_BLOCK - 1) / EDGES_PER_BLOCK;
    const int n4 = (int)(ND / 4);
    const int nbh = (n4 + 255) / 256;
    const int nbw = (WTOT + 255) / 256;
    const int nbc = (NB + 255) / 256;
    prep_kernel<<<nbh + nbw + nbc, 256, 0, stream>>>(
        x, hhalf, n4, W1, W2, Wph, Wpl, WTOT, gcursor, NB, nbh, nbw);
    bucket_scatter_kernel<<<EB, 256, 0, stream>>>(esrc, edst, gcursor, staging, E, NB);
    bucket_build_kernel<<<NB, 256, 0, stream>>>(staging, gcursor, rowstart, rowend, col, N);

    const int gemm_grid = (N + 63) / 64;
    for (int l = 0; l < L; ++l) {
        float* colsum = colsum4 + (size_t)l * NREP * 2 * D;
        gemm_mfma<true, false, true, false, 4><<<gemm_grid, 256, 0, stream>>>(
            hhalf, rowstart, rowend, col, nullptr,
            Wph + (size_t)(l * 2) * D * D, Wpl + (size_t)(l * 2) * D * D,
            b1 + (size_t)l * D, nullptr, nullptr, nullptr, z16, colsum,
            nullptr, nullptr, nullptr, N);
        if (l < L - 1) {
            gemm_mfma<false, true, false, false, 8><<<gemm_grid, 256, 0, stream>>>(
                nullptr, nullptr, nullptr, nullptr, z16,
                Wph + (size_t)(l * 2 + 1) * D * D, Wpl + (size_t)(l * 2 + 1) * D * D,
                b2 + (size_t)l * D, colsum, gamma + (size_t)l * D, beta + (size_t)l * D,
                hhalf, nullptr, nullptr, nullptr, nullptr, N);
        } else {
            gemm_mfma<false, true, false, true, 8><<<gemm_grid, 256, 0, stream>>>(
                nullptr, nullptr, nullptr, nullptr, z16,
                Wph + (size_t)(l * 2 + 1) * D * D, Wpl + (size_t)(l * 2 + 1) * D * D,
                b2 + (size_t)l * D, colsum, gamma + (size_t)l * D, beta + (size_t)l * D,
                nullptr, nullptr, batch, pooled, cnt, N);
        }
    }

    final_linear_kernel<<<(G * 2 + 255) / 256, 256, 0, stream>>>(pooled, cnt, linW, linb, out, G);
}